// Round 5
// baseline (117.175 us; speedup 1.0000x reference)
//
#include <hip/hip_runtime.h>

#define HW 2304          // 48*48
#define HW4 576          // HW/4
#define PART_STRIDE 2308 // 2304 A-partials + 1 sq, padded to mult of 4
#define S1_T 512         // stage-1 threads/block (8 waves; 4 blocks/CU = 100%)

// Stage 1 (v5): canonical streaming shape. 512 blocks x 512 threads,
// grid-stride over CONTIGUOUS 8KB chunks (chip-wide linear sweep, like the
// 6.3TB/s copy probe). |diff| accumulates into LDS via ds_add_f32; the
// component-split As[4][576] layout makes lanes hit consecutive banks
// (conflict-free), decoupling block shape from the hw-phase constraint
// that forced 9-wave blocks (and 40-53% occupancy) in rounds 1-4.
__global__ __launch_bounds__(S1_T, 8) void sc_stage1(
    const float4* __restrict__ out4, const float4* __restrict__ tgt4,
    float* __restrict__ part, int N4, int step, int pstep)
{
    __shared__ float As[4][HW4];
    __shared__ float wsum[8];
    int tid = threadIdx.x;
    int blk = blockIdx.x;

    for (int k = tid; k < 4 * HW4; k += S1_T) (&As[0][0])[k] = 0.f;
    __syncthreads();

    float sq = 0.f;
    int i = blk * S1_T + tid;      // global float4 index
    int p = i % HW4;               // hw phase (one div at entry)
    for (; i < N4; i += step) {
        float4 o = out4[i];
        float4 t = tgt4[i];
        float d0 = o.x - t.x, d1 = o.y - t.y, d2 = o.z - t.z, d3 = o.w - t.w;
        sq = fmaf(d0, d0, sq);
        sq = fmaf(d1, d1, sq);
        sq = fmaf(d2, d2, sq);
        sq = fmaf(d3, d3, sq);
        atomicAdd(&As[0][p], fabsf(d0));   // ds_add_f32, consecutive banks
        atomicAdd(&As[1][p], fabsf(d1));
        atomicAdd(&As[2][p], fabsf(d2));
        atomicAdd(&As[3][p], fabsf(d3));
        p += pstep; if (p >= HW4) p -= HW4;
    }
    __syncthreads();

    // writeback LDS partial -> part row (hw = 4*p + c  <->  As[c][p])
    float* pbase = part + (size_t)blk * PART_STRIDE;
    for (int k = tid; k < HW; k += S1_T)
        pbase[k] = As[k & 3][k >> 2];

    // block-reduce sq (8 waves)
    #pragma unroll
    for (int off = 32; off; off >>= 1) sq += __shfl_down(sq, off);
    if ((tid & 63) == 0) wsum[tid >> 6] = sq;
    __syncthreads();
    if (tid == 0) {
        float s = 0.f;
        #pragma unroll
        for (int w = 0; w < 8; ++w) s += wsum[w];
        pbase[HW] = s;
    }
}

// Stage 2: 36 column blocks x 1024 threads = 64 hw-lanes x 16 row-groups.
// Each thread sums NB/16 rows; 16-way LDS reduce per hw. Block 36 reduces
// the per-block sq partials -> MSE into out[0] (plain store: idempotent
// across graph replays).
__global__ __launch_bounds__(1024) void sc_stage2(
    const float* __restrict__ part, float* __restrict__ A,
    float* __restrict__ out, int NB, int B, float invN)
{
    __shared__ float red[16][64];
    int lane = threadIdx.x & 63;
    int grp  = threadIdx.x >> 6;   // 0..15
    int blk  = blockIdx.x;
    if (blk < 36) {
        int hw = blk * 64 + lane;  // 64 consecutive floats per wave: coalesced
        float s = 0.f;
        for (int r = grp; r < NB; r += 16)
            s += part[(size_t)r * PART_STRIDE + hw];
        red[grp][lane] = s;
        __syncthreads();
        if (grp == 0) {
            float t = 0.f;
            #pragma unroll
            for (int g = 0; g < 16; ++g) t += red[g][lane];
            A[hw] = t / (float)B;
        }
    } else {
        float s = (threadIdx.x < NB)
                    ? part[(size_t)threadIdx.x * PART_STRIDE + HW] : 0.f;
        #pragma unroll
        for (int off = 32; off; off >>= 1) s += __shfl_down(s, off);
        if ((threadIdx.x & 63) == 0) red[0][grp] = s;
        __syncthreads();
        if (threadIdx.x == 0) {
            float t = 0.f;
            #pragma unroll
            for (int g = 0; g < 16; ++g) t += red[0][g];
            out[0] = t * invN;
        }
    }
}

// Stage 3: one block per (i,j): l1 = (A . |psu_ij|)/HW, then
// out += 0.5*mu*l1^2 (54 atomic adds; fp ordering noise ~1e-7 << threshold).
__global__ __launch_bounds__(256) void sc_stage3(
    const float* __restrict__ A, const float* __restrict__ psu,
    const float* __restrict__ mu, float* __restrict__ out)
{
    int j = blockIdx.x;
    int tid = threadIdx.x;
    const float* p = psu + (size_t)j * HW;
    float s = 0.f;
    for (int hw = tid; hw < HW; hw += 256) s += A[hw] * fabsf(p[hw]);
    #pragma unroll
    for (int off = 32; off; off >>= 1) s += __shfl_down(s, off);
    __shared__ float wsum[4];
    if ((tid & 63) == 0) wsum[tid >> 6] = s;
    __syncthreads();
    if (tid == 0) {
        float l1 = (wsum[0] + wsum[1] + wsum[2] + wsum[3]) * (1.0f / HW);
        float contrib = 0.5f * mu[j] * l1 * l1;   // GAMMA = 1
        atomicAdd(out, contrib);
    }
}

extern "C" void kernel_launch(void* const* d_in, const int* in_sizes, int n_in,
                              void* d_out, int out_size, void* d_ws, size_t ws_size,
                              hipStream_t stream)
{
    const float* outp = (const float*)d_in[0];
    const float* tgtp = (const float*)d_in[1];
    const float* psu  = (const float*)d_in[2];
    const float* mu   = (const float*)d_in[3];

    int B   = in_sizes[0] / HW;     // 8192
    int nij = in_sizes[3];          // 54
    int N4  = in_sizes[0] / 4;      // total float4 count (B*HW4)

    int NB = 512;                   // stage-1 blocks; shrink if ws too small
    while (NB > 64 &&
           ((size_t)NB * PART_STRIDE + HW) * sizeof(float) > ws_size)
        NB >>= 1;

    float* part = (float*)d_ws;
    float* A    = part + (size_t)NB * PART_STRIDE;
    float invN  = 1.0f / ((float)B * (float)HW);

    int step  = NB * S1_T;          // grid stride in float4
    int pstep = step % HW4;         // phase advance per stride

    sc_stage1<<<NB, S1_T, 0, stream>>>((const float4*)outp, (const float4*)tgtp,
                                       part, N4, step, pstep);
    sc_stage2<<<37, 1024, 0, stream>>>(part, A, (float*)d_out, NB, B, invN);
    sc_stage3<<<nij, 256, 0, stream>>>(A, psu, mu, (float*)d_out);
}